// Round 9
// baseline (784.385 us; speedup 1.0000x reference)
//
#include <hip/hip_runtime.h>
#include <hip/hip_bf16.h>
#include <hip/hip_cooperative_groups.h>

namespace cg = cooperative_groups;

#define N_NODES 50000
#define N_EDGES 800000
#define EPS 1e-5f
#define SCAN_BLOCKS 49  // 49 * 1024 = 50176 >= N_NODES
#define BUILD_BLOCKS 1024

typedef __attribute__((ext_vector_type(8))) short short8;
typedef __attribute__((ext_vector_type(4))) float f32x4;

static __device__ __forceinline__ unsigned short f2bf(float f) {
  union { float f; unsigned u; } v; v.f = f;
  const unsigned r = v.u + 0x7FFF + ((v.u >> 16) & 1);  // RNE
  return (unsigned short)(r >> 16);
}

// ---------------- cooperative build: prepw+zero -> count -> scan -> place -> gather ----------------
__global__ void __launch_bounds__(256) k_build(
    const float* __restrict__ W0, const float* __restrict__ W1,
    const float* __restrict__ Wc0,
    unsigned short* __restrict__ W0T, unsigned short* __restrict__ W1T,
    unsigned short* __restrict__ Wc0T,
    const int* __restrict__ ei, const float* __restrict__ ea,
    int* __restrict__ cnt, int* __restrict__ starts, int* __restrict__ pos,
    int* __restrict__ bsum, int* __restrict__ csr,
    unsigned short* __restrict__ aggb) {
  cg::grid_group grid = cg::this_grid();
  __shared__ int lds[256];
  __shared__ int s_off;
  const int t = threadIdx.x, b = blockIdx.x;
  const int gid = b * 256 + t;
  const int nthreads = BUILD_BLOCKS * 256;

  // ---- phase 0: weight transpose+bf16, zero cnt ----
  for (int idx = gid; idx < 128 * 128; idx += nthreads) {
    const int n = idx >> 7, k = idx & 127;
    W0T[idx] = f2bf(W0[k * 128 + n]);
  }
  for (int idx = gid; idx < 64 * 192; idx += nthreads) {
    const int n = idx / 192, k = idx - n * 192;
    W1T[idx] = f2bf(W1[k * 64 + n]);
  }
  for (int idx = gid; idx < 64 * 128; idx += nthreads) {
    const int n = idx >> 7, k = idx & 127;
    Wc0T[idx] = f2bf(Wc0[k * 64 + n]);
  }
  for (int i = gid; i < N_NODES; i += nthreads) cnt[i] = 0;
  grid.sync();

  // ---- phase 1: count ----
  for (int e = gid; e < N_EDGES; e += nthreads)
    atomicAdd(&cnt[ei[N_EDGES + e]], 1);
  grid.sync();

  // ---- phase 2: per-block scan (blocks 0..48), block sums -> bsum ----
  if (b < SCAN_BLOCKS) {
    const int base = b * 1024 + t * 4;
    int c0 = 0, c1 = 0, c2 = 0, c3 = 0;
    if (base + 3 < N_NODES) {
      const int4 c = *(const int4*)(cnt + base);
      c0 = c.x; c1 = c.y; c2 = c.z; c3 = c.w;
    } else {
      if (base + 0 < N_NODES) c0 = cnt[base + 0];
      if (base + 1 < N_NODES) c1 = cnt[base + 1];
      if (base + 2 < N_NODES) c2 = cnt[base + 2];
      if (base + 3 < N_NODES) c3 = cnt[base + 3];
    }
    const int s = c0 + c1 + c2 + c3;
    lds[t] = s;
    __syncthreads();
    for (int off = 1; off < 256; off <<= 1) {
      const int v = (t >= off) ? lds[t - off] : 0;
      __syncthreads();
      lds[t] += v;
      __syncthreads();
    }
    int run = lds[t] - s;
    if (t == 255) bsum[b] = lds[255];
    const int o0 = run; run += c0;
    const int o1 = run; run += c1;
    const int o2 = run; run += c2;
    const int o3 = run;
    if (base + 3 < N_NODES) {
      *(int4*)(starts + base) = make_int4(o0, o1, o2, o3);
    } else {
      if (base + 0 < N_NODES) starts[base + 0] = o0;
      if (base + 1 < N_NODES) starts[base + 1] = o1;
      if (base + 2 < N_NODES) starts[base + 2] = o2;
      if (base + 3 < N_NODES) starts[base + 3] = o3;
    }
  }
  grid.sync();

  // ---- phase 3: add block offsets (blocks 0..48) ----
  if (b < SCAN_BLOCKS) {
    if (t < 64) {
      int v = (t < b) ? bsum[t] : 0;
      for (int o = 32; o; o >>= 1) v += __shfl_xor(v, o);
      if (t == 0) s_off = v;
    }
    __syncthreads();
    const int off = s_off;
    const int base = b * 1024 + t * 4;
    if (base + 3 < N_NODES) {
      int4 v = *(const int4*)(starts + base);
      v.x += off; v.y += off; v.z += off; v.w += off;
      *(int4*)(starts + base) = v;
      *(int4*)(pos + base) = v;
    } else {
      for (int i = 0; i < 4; ++i)
        if (base + i < N_NODES) {
          const int v = starts[base + i] + off;
          starts[base + i] = v;
          pos[base + i] = v;
        }
    }
    if (b == 0 && t == 0) starts[N_NODES] = N_EDGES;
  }
  grid.sync();

  // ---- phase 4: place edge ids into CSR ----
  for (int e = gid; e < N_EDGES; e += nthreads) {
    const int d = ei[N_EDGES + e];
    const int slot = atomicAdd(&pos[d], 1);
    csr[slot] = e;
  }
  grid.sync();

  // ---- phase 5: gather-mean -> aggb (bf16); one wave per node ----
  {
    const int lane = t & 63;
    const int wv = t >> 6;
    const int wstride = BUILD_BLOCKS * 4;
    for (int n = b * 4 + wv; n < N_NODES; n += wstride) {
      const int s0 = starts[n], s1 = starts[n + 1];
      float sum = 0.0f;
      int i = s0;
      for (; i + 7 < s1; i += 8) {
        int e[8];
#pragma unroll
        for (int j = 0; j < 8; ++j) e[j] = csr[i + j];
        float a[8];
#pragma unroll
        for (int j = 0; j < 8; ++j) a[j] = ea[(size_t)e[j] * 64 + lane];
        sum += ((a[0] + a[1]) + (a[2] + a[3])) + ((a[4] + a[5]) + (a[6] + a[7]));
      }
      for (; i + 3 < s1; i += 4) {
        const int e0 = csr[i], e1 = csr[i + 1], e2 = csr[i + 2], e3 = csr[i + 3];
        const float a0 = ea[(size_t)e0 * 64 + lane];
        const float a1 = ea[(size_t)e1 * 64 + lane];
        const float a2 = ea[(size_t)e2 * 64 + lane];
        const float a3 = ea[(size_t)e3 * 64 + lane];
        sum += (a0 + a1) + (a2 + a3);
      }
      for (; i < s1; ++i) sum += ea[(size_t)csr[i] * 64 + lane];
      const int deg = s1 - s0;
      aggb[(size_t)n * 64 + lane] = f2bf(sum / (float)max(deg, 1));
    }
  }
}

// ---------------- fused node MLP: L0 -> LN -> L1 -> LN -> zb (bf16) ----------------
__global__ void __launch_bounds__(256) k_nodes(
    const float* __restrict__ x, const unsigned short* __restrict__ aggb,
    const unsigned short* __restrict__ W0T, const float* __restrict__ b0,
    const float* __restrict__ g0, const float* __restrict__ be0,
    const unsigned short* __restrict__ W1T, const float* __restrict__ b1,
    const float* __restrict__ g1, const float* __restrict__ be1,
    unsigned short* __restrict__ zb) {
  __shared__ char A0[64 * 256];   // [64][128] bf16, 256B rows, XOR-swizzled
  __shared__ char A1[64 * 384];   // [64][192] bf16, 384B rows, XOR-swizzled
  __shared__ float red0[64][4], red1[64][4];

  const int t = threadIdx.x;
  const int lane = t & 63;
  const int w = t >> 6;
  const int m = lane & 15;
  const int g = lane >> 4;
  const int nbase = blockIdx.x * 64;

  {
    const int row = t >> 2, seg = t & 3;
    const int node = nbase + row;
    const int swz = (row & 7) << 4;
    unsigned short h[16];
    if (node < N_NODES) {
      const float4* xr = (const float4*)(x + (size_t)node * 64 + seg * 16);
#pragma unroll
      for (int i = 0; i < 4; ++i) {
        const float4 v = xr[i];
        h[4 * i + 0] = f2bf(v.x); h[4 * i + 1] = f2bf(v.y);
        h[4 * i + 2] = f2bf(v.z); h[4 * i + 3] = f2bf(v.w);
      }
    } else {
#pragma unroll
      for (int i = 0; i < 16; ++i) h[i] = 0;
    }
    uint4 lo, hi;
    unsigned* lp = (unsigned*)&lo;
    unsigned* hp = (unsigned*)&hi;
#pragma unroll
    for (int i = 0; i < 4; ++i) lp[i] = (unsigned)h[2 * i] | ((unsigned)h[2 * i + 1] << 16);
#pragma unroll
    for (int i = 0; i < 4; ++i) hp[i] = (unsigned)h[8 + 2 * i] | ((unsigned)h[8 + 2 * i + 1] << 16);
    *(uint4*)(A0 + row * 256 + ((seg * 32) ^ swz)) = lo;
    *(uint4*)(A0 + row * 256 + ((seg * 32 + 16) ^ swz)) = hi;
    uint4 a0v = make_uint4(0, 0, 0, 0), a1v = make_uint4(0, 0, 0, 0);
    if (node < N_NODES) {
      const uint4* ap = (const uint4*)(aggb + (size_t)node * 64 + seg * 16);
      a0v = ap[0]; a1v = ap[1];
    }
    *(uint4*)(A0 + row * 256 + ((128 + seg * 32) ^ swz)) = a0v;
    *(uint4*)(A0 + row * 256 + ((128 + seg * 32 + 16) ^ swz)) = a1v;
    *(uint4*)(A1 + row * 384 + ((256 + seg * 32) ^ swz)) = a0v;
    *(uint4*)(A1 + row * 384 + ((256 + seg * 32 + 16) ^ swz)) = a1v;
  }

  short8 B0[4][2];
#pragma unroll
  for (int ks = 0; ks < 4; ++ks)
#pragma unroll
    for (int nt = 0; nt < 2; ++nt) {
      const int n = w * 32 + nt * 16 + m;
      B0[ks][nt] = *(const short8*)(W0T + n * 128 + ks * 32 + 8 * g);
    }

  __syncthreads();

  f32x4 acc0[4][2];
#pragma unroll
  for (int mt = 0; mt < 4; ++mt)
#pragma unroll
    for (int nt = 0; nt < 2; ++nt) acc0[mt][nt] = (f32x4){0.f, 0.f, 0.f, 0.f};
#pragma unroll
  for (int ks = 0; ks < 4; ++ks)
#pragma unroll
    for (int mt = 0; mt < 4; ++mt) {
      const int row = 16 * mt + m;
      const short8 a = *(const short8*)(A0 + row * 256 + ((ks * 64 + g * 16) ^ ((row & 7) << 4)));
      acc0[mt][0] = __builtin_amdgcn_mfma_f32_16x16x32_bf16(a, B0[ks][0], acc0[mt][0], 0, 0, 0);
      acc0[mt][1] = __builtin_amdgcn_mfma_f32_16x16x32_bf16(a, B0[ks][1], acc0[mt][1], 0, 0, 0);
    }

  float b0c[2], g0c[2], be0c[2];
#pragma unroll
  for (int nt = 0; nt < 2; ++nt) {
    const int c = w * 32 + nt * 16 + m;
    b0c[nt] = b0[c]; g0c[nt] = g0[c]; be0c[nt] = be0[c];
  }
  float ps1[4][4], ps2[4][4];
#pragma unroll
  for (int mt = 0; mt < 4; ++mt)
#pragma unroll
    for (int q = 0; q < 4; ++q) {
      const float v0 = fmaxf(acc0[mt][0][q] + b0c[0], 0.f);
      const float v1 = fmaxf(acc0[mt][1][q] + b0c[1], 0.f);
      ps1[mt][q] = v0 + v1;
      ps2[mt][q] = v0 * v0 + v1 * v1;
    }
#pragma unroll
  for (int mask = 1; mask <= 8; mask <<= 1)
#pragma unroll
    for (int mt = 0; mt < 4; ++mt)
#pragma unroll
      for (int q = 0; q < 4; ++q) {
        ps1[mt][q] += __shfl_xor(ps1[mt][q], mask);
        ps2[mt][q] += __shfl_xor(ps2[mt][q], mask);
      }
  if (m == 0) {
#pragma unroll
    for (int mt = 0; mt < 4; ++mt)
#pragma unroll
      for (int q = 0; q < 4; ++q) {
        const int row = 16 * mt + 4 * g + q;
        red0[row][w] = ps1[mt][q];
        red1[row][w] = ps2[mt][q];
      }
  }
  __syncthreads();

#pragma unroll
  for (int mt = 0; mt < 4; ++mt)
#pragma unroll
    for (int q = 0; q < 4; ++q) {
      const int row = 16 * mt + 4 * g + q;
      const float4 r0 = *(const float4*)red0[row];
      const float4 r1 = *(const float4*)red1[row];
      const float S1 = (r0.x + r0.y) + (r0.z + r0.w);
      const float S2 = (r1.x + r1.y) + (r1.z + r1.w);
      const float mean = S1 * (1.0f / 128.0f);
      const float var = S2 * (1.0f / 128.0f) - mean * mean;
      const float inv = rsqrtf(var + EPS);
#pragma unroll
      for (int nt = 0; nt < 2; ++nt) {
        const float v = fmaxf(acc0[mt][nt][q] + b0c[nt], 0.f);
        const float o = (v - mean) * inv * g0c[nt] + be0c[nt];
        const int col = w * 32 + nt * 16 + m;
        *(unsigned short*)(A1 + row * 384 + ((2 * col) ^ ((row & 7) << 4))) = f2bf(o);
      }
    }

  short8 B1[6];
  {
    const int n = w * 16 + m;
#pragma unroll
    for (int ks = 0; ks < 6; ++ks)
      B1[ks] = *(const short8*)(W1T + n * 192 + ks * 32 + 8 * g);
  }
  __syncthreads();

  f32x4 acc1[4];
#pragma unroll
  for (int mt = 0; mt < 4; ++mt) acc1[mt] = (f32x4){0.f, 0.f, 0.f, 0.f};
#pragma unroll
  for (int ks = 0; ks < 6; ++ks)
#pragma unroll
    for (int mt = 0; mt < 4; ++mt) {
      const int row = 16 * mt + m;
      const short8 a = *(const short8*)(A1 + row * 384 + ((ks * 64 + g * 16) ^ ((row & 7) << 4)));
      acc1[mt] = __builtin_amdgcn_mfma_f32_16x16x32_bf16(a, B1[ks], acc1[mt], 0, 0, 0);
    }

  const int c1i = w * 16 + m;
  const float b1c = b1[c1i], g1c = g1[c1i], be1c = be1[c1i];
  float qs1[4][4], qs2[4][4];
#pragma unroll
  for (int mt = 0; mt < 4; ++mt)
#pragma unroll
    for (int q = 0; q < 4; ++q) {
      const float v = fmaxf(acc1[mt][q] + b1c, 0.f);
      qs1[mt][q] = v;
      qs2[mt][q] = v * v;
    }
#pragma unroll
  for (int mask = 1; mask <= 8; mask <<= 1)
#pragma unroll
    for (int mt = 0; mt < 4; ++mt)
#pragma unroll
      for (int q = 0; q < 4; ++q) {
        qs1[mt][q] += __shfl_xor(qs1[mt][q], mask);
        qs2[mt][q] += __shfl_xor(qs2[mt][q], mask);
      }
  if (m == 0) {
#pragma unroll
    for (int mt = 0; mt < 4; ++mt)
#pragma unroll
      for (int q = 0; q < 4; ++q) {
        const int row = 16 * mt + 4 * g + q;
        red0[row][w] = qs1[mt][q];
        red1[row][w] = qs2[mt][q];
      }
  }
  __syncthreads();
#pragma unroll
  for (int mt = 0; mt < 4; ++mt)
#pragma unroll
    for (int q = 0; q < 4; ++q) {
      const int row = 16 * mt + 4 * g + q;
      const int node = nbase + row;
      const float4 r0 = *(const float4*)red0[row];
      const float4 r1 = *(const float4*)red1[row];
      const float S1 = (r0.x + r0.y) + (r0.z + r0.w);
      const float S2 = (r1.x + r1.y) + (r1.z + r1.w);
      const float mean = S1 * (1.0f / 64.0f);
      const float var = S2 * (1.0f / 64.0f) - mean * mean;
      const float inv = rsqrtf(var + EPS);
      const float v = fmaxf(acc1[mt][q] + b1c, 0.f);
      const float o = (v - mean) * inv * g1c + be1c;
      if (node < N_NODES) zb[(size_t)node * 64 + c1i] = f2bf(o);
    }
}

// ---------------- edge classifier: LDS-free direct-gather MFMA (R7 form) ----------------
__global__ void __launch_bounds__(256) k_cls_mfma(
    const unsigned short* __restrict__ zb, const int* __restrict__ ei,
    const unsigned short* __restrict__ Wc0T, const float* __restrict__ bc0,
    const float* __restrict__ Wc1, const float* __restrict__ bc1,
    float* __restrict__ out) {
  const int t = threadIdx.x;
  const int lane = t & 63;
  const int w = t >> 6;
  const int m = lane & 15;
  const int g = lane >> 4;

  short8 bfrag[4][4];
#pragma unroll
  for (int ks = 0; ks < 4; ++ks)
#pragma unroll
    for (int nt = 0; nt < 4; ++nt)
      bfrag[ks][nt] = *(const short8*)(Wc0T + (nt * 16 + m) * 128 + ks * 32 + 8 * g);
  float wc1v0[4], wc1v1[4], bc0v[4];
#pragma unroll
  for (int nt = 0; nt < 4; ++nt) {
    const int j = nt * 16 + m;
    wc1v0[nt] = Wc1[j * 2 + 0];
    wc1v1[nt] = Wc1[j * 2 + 1];
    bc0v[nt] = bc0[j];
  }
  const float ob0 = bc1[0], ob1 = bc1[1];

  const int gstride = gridDim.x * 4;
  for (int grp = blockIdx.x * 4 + w; grp < N_EDGES / 16; grp += gstride) {
    const int ebase = grp * 16;
    const int e = ebase + m;
    const int s = ei[e], d = ei[N_EDGES + e];
    const short8 a0 = *(const short8*)(zb + (size_t)s * 64 + 8 * g);
    const short8 a1 = *(const short8*)(zb + (size_t)s * 64 + 32 + 8 * g);
    const short8 a2 = *(const short8*)(zb + (size_t)d * 64 + 8 * g);
    const short8 a3 = *(const short8*)(zb + (size_t)d * 64 + 32 + 8 * g);

    f32x4 acc0 = {0.f, 0.f, 0.f, 0.f}, acc1 = acc0, acc2 = acc0, acc3 = acc0;
    acc0 = __builtin_amdgcn_mfma_f32_16x16x32_bf16(a0, bfrag[0][0], acc0, 0, 0, 0);
    acc1 = __builtin_amdgcn_mfma_f32_16x16x32_bf16(a0, bfrag[0][1], acc1, 0, 0, 0);
    acc2 = __builtin_amdgcn_mfma_f32_16x16x32_bf16(a0, bfrag[0][2], acc2, 0, 0, 0);
    acc3 = __builtin_amdgcn_mfma_f32_16x16x32_bf16(a0, bfrag[0][3], acc3, 0, 0, 0);
    acc0 = __builtin_amdgcn_mfma_f32_16x16x32_bf16(a1, bfrag[1][0], acc0, 0, 0, 0);
    acc1 = __builtin_amdgcn_mfma_f32_16x16x32_bf16(a1, bfrag[1][1], acc1, 0, 0, 0);
    acc2 = __builtin_amdgcn_mfma_f32_16x16x32_bf16(a1, bfrag[1][2], acc2, 0, 0, 0);
    acc3 = __builtin_amdgcn_mfma_f32_16x16x32_bf16(a1, bfrag[1][3], acc3, 0, 0, 0);
    acc0 = __builtin_amdgcn_mfma_f32_16x16x32_bf16(a2, bfrag[2][0], acc0, 0, 0, 0);
    acc1 = __builtin_amdgcn_mfma_f32_16x16x32_bf16(a2, bfrag[2][1], acc1, 0, 0, 0);
    acc2 = __builtin_amdgcn_mfma_f32_16x16x32_bf16(a2, bfrag[2][2], acc2, 0, 0, 0);
    acc3 = __builtin_amdgcn_mfma_f32_16x16x32_bf16(a2, bfrag[2][3], acc3, 0, 0, 0);
    acc0 = __builtin_amdgcn_mfma_f32_16x16x32_bf16(a3, bfrag[3][0], acc0, 0, 0, 0);
    acc1 = __builtin_amdgcn_mfma_f32_16x16x32_bf16(a3, bfrag[3][1], acc1, 0, 0, 0);
    acc2 = __builtin_amdgcn_mfma_f32_16x16x32_bf16(a3, bfrag[3][2], acc2, 0, 0, 0);
    acc3 = __builtin_amdgcn_mfma_f32_16x16x32_bf16(a3, bfrag[3][3], acc3, 0, 0, 0);

    float p0[4], p1[4];
#pragma unroll
    for (int r = 0; r < 4; ++r) {
      const float h0v = fmaxf(acc0[r] + bc0v[0], 0.f);
      const float h1v = fmaxf(acc1[r] + bc0v[1], 0.f);
      const float h2v = fmaxf(acc2[r] + bc0v[2], 0.f);
      const float h3v = fmaxf(acc3[r] + bc0v[3], 0.f);
      p0[r] = h0v * wc1v0[0] + h1v * wc1v0[1] + h2v * wc1v0[2] + h3v * wc1v0[3];
      p1[r] = h0v * wc1v1[0] + h1v * wc1v1[1] + h2v * wc1v1[2] + h3v * wc1v1[3];
    }
#pragma unroll
    for (int mask = 1; mask <= 8; mask <<= 1)
#pragma unroll
      for (int r = 0; r < 4; ++r) {
        p0[r] += __shfl_xor(p0[r], mask);
        p1[r] += __shfl_xor(p1[r], mask);
      }
    const int eout = ebase + g * 4;
#pragma unroll
    for (int r = 0; r < 4; ++r) {
      if (m == 2 * r) out[(size_t)(eout + r) * 2 + 0] = p0[r] + ob0;
      if (m == 2 * r + 1) out[(size_t)(eout + r) * 2 + 1] = p1[r] + ob1;
    }
  }
}

extern "C" void kernel_launch(void* const* d_in, const int* in_sizes, int n_in,
                              void* d_out, int out_size, void* d_ws, size_t ws_size,
                              hipStream_t stream) {
  const float* x   = (const float*)d_in[0];
  const int*   ei  = (const int*)d_in[1];
  const float* ea  = (const float*)d_in[2];
  const float* W0  = (const float*)d_in[3];
  const float* b0  = (const float*)d_in[4];
  const float* g0  = (const float*)d_in[5];
  const float* be0 = (const float*)d_in[6];
  const float* W1  = (const float*)d_in[7];
  const float* b1  = (const float*)d_in[8];
  const float* g1  = (const float*)d_in[9];
  const float* be1 = (const float*)d_in[10];
  const float* Wc0 = (const float*)d_in[11];
  const float* bc0 = (const float*)d_in[12];
  const float* Wc1 = (const float*)d_in[13];
  const float* bc1 = (const float*)d_in[14];
  float* out = (float*)d_out;

  char* base = (char*)d_ws;
  unsigned short* zb   = (unsigned short*)base;                       // N*64 bf16
  unsigned short* aggb = zb + (size_t)N_NODES * 64;                   // N*64 bf16
  unsigned short* W0T  = aggb + (size_t)N_NODES * 64;                 // 128*128
  unsigned short* W1T  = W0T + 128 * 128;                             // 64*192
  unsigned short* Wc0T = W1T + 64 * 192;                              // 64*128
  int* cnt    = (int*)(Wc0T + 64 * 128);                              // N
  int* starts = cnt + N_NODES;                                        // N+1 (+pad)
  int* pos    = starts + N_NODES + 4;                                 // N
  int* bsum   = pos + N_NODES;                                        // 64
  int* csr    = bsum + 64;                                            // E

  void* args[] = {
    (void*)&W0, (void*)&W1, (void*)&Wc0,
    (void*)&W0T, (void*)&W1T, (void*)&Wc0T,
    (void*)&ei, (void*)&ea,
    (void*)&cnt, (void*)&starts, (void*)&pos,
    (void*)&bsum, (void*)&csr, (void*)&aggb
  };
  hipLaunchCooperativeKernel((void*)k_build, dim3(BUILD_BLOCKS), dim3(256),
                             args, 0, stream);
  k_nodes<<<(N_NODES + 63) / 64, 256, 0, stream>>>(x, aggb, W0T, b0, g0, be0,
                                                   W1T, b1, g1, be1, zb);
  k_cls_mfma<<<12500, 256, 0, stream>>>(zb, ei, Wc0T, bc0, Wc1, bc1, out);
}

// Round 10
// 389.511 us; speedup vs baseline: 2.0138x; 2.0138x over previous
//
#include <hip/hip_runtime.h>
#include <hip/hip_bf16.h>

#define N_NODES 50000
#define N_EDGES 800000
#define EPS 1e-5f
#define SCAN_BLOCKS 49  // 49 * 1024 = 50176 >= N_NODES

typedef __attribute__((ext_vector_type(8))) short short8;
typedef __attribute__((ext_vector_type(4))) float f32x4;

static __device__ __forceinline__ unsigned short f2bf(float f) {
  union { float f; unsigned u; } v; v.f = f;
  const unsigned r = v.u + 0x7FFF + ((v.u >> 16) & 1);  // RNE
  return (unsigned short)(r >> 16);
}

// ---------------- fused: weight prep (transpose+bf16) + cnt zero + degree count ----------------
// grid covers E (3125 blocks); blocks 0..63 also handle the weight/zero work.
__global__ void __launch_bounds__(256) k_prep_count(
    const float* __restrict__ W0, const float* __restrict__ W1,
    const float* __restrict__ Wc0,
    unsigned short* __restrict__ W0T, unsigned short* __restrict__ W1T,
    unsigned short* __restrict__ Wc0T,
    const int* __restrict__ ei, int* __restrict__ cnt) {
  const int idx = blockIdx.x * 256 + threadIdx.x;
  if (idx < 128 * 128) {
    const int n = idx >> 7, k = idx & 127;
    W0T[idx] = f2bf(W0[k * 128 + n]);
  }
  if (idx < 64 * 192) {
    const int n = idx / 192, k = idx - n * 192;
    W1T[idx] = f2bf(W1[k * 64 + n]);
  }
  if (idx < 64 * 128) {
    const int n = idx >> 7, k = idx & 127;
    Wc0T[idx] = f2bf(Wc0[k * 64 + n]);
  }
  if (idx < N_NODES) cnt[idx] = 0;   // covered: 3125*256 = 800000 >= N_NODES
  __threadfence();
  // count phase must see zeroed cnt: zero is done by the same or earlier-indexed
  // threads; but cross-block ordering is NOT guaranteed, so count goes below a
  // device-wide dependency via a separate dispatch... except all zeroing here is
  // done by threads idx<N_NODES and counting touches the same buffer. To stay
  // correct without a fence we split: counting happens in k_count2 below.
}

__global__ void k_count2(const int* __restrict__ ei, int* __restrict__ cnt) {
  const int e = blockIdx.x * blockDim.x + threadIdx.x;
  if (e < N_EDGES) atomicAdd(&cnt[ei[N_EDGES + e]], 1);
}

__global__ void __launch_bounds__(256) k_scan_blk(const int* __restrict__ cnt,
                                                  int* __restrict__ starts,
                                                  int* __restrict__ bsum) {
  __shared__ int lds[256];
  const int t = threadIdx.x, b = blockIdx.x;
  const int base = b * 1024 + t * 4;
  int c0 = 0, c1 = 0, c2 = 0, c3 = 0;
  if (base + 3 < N_NODES) {
    const int4 c = *(const int4*)(cnt + base);
    c0 = c.x; c1 = c.y; c2 = c.z; c3 = c.w;
  } else {
    if (base + 0 < N_NODES) c0 = cnt[base + 0];
    if (base + 1 < N_NODES) c1 = cnt[base + 1];
    if (base + 2 < N_NODES) c2 = cnt[base + 2];
    if (base + 3 < N_NODES) c3 = cnt[base + 3];
  }
  const int s = c0 + c1 + c2 + c3;
  lds[t] = s;
  __syncthreads();
  for (int off = 1; off < 256; off <<= 1) {
    const int v = (t >= off) ? lds[t - off] : 0;
    __syncthreads();
    lds[t] += v;
    __syncthreads();
  }
  int run = lds[t] - s;
  if (t == 255) bsum[b] = lds[255];  // block total
  const int o0 = run; run += c0;
  const int o1 = run; run += c1;
  const int o2 = run; run += c2;
  const int o3 = run;
  if (base + 3 < N_NODES) {
    *(int4*)(starts + base) = make_int4(o0, o1, o2, o3);
  } else {
    if (base + 0 < N_NODES) starts[base + 0] = o0;
    if (base + 1 < N_NODES) starts[base + 1] = o1;
    if (base + 2 < N_NODES) starts[base + 2] = o2;
    if (base + 3 < N_NODES) starts[base + 3] = o3;
  }
}

// adds sum(bsum[0..b)) computed in-kernel (49 values, one wave-reduce)
__global__ void __launch_bounds__(256) k_scan_add(int* __restrict__ starts,
                                                  int* __restrict__ pos,
                                                  const int* __restrict__ bsum) {
  __shared__ int s_off;
  const int t = threadIdx.x, b = blockIdx.x;
  if (t < 64) {
    int v = (t < b) ? bsum[t] : 0;  // b <= 48 < 64
    for (int o = 32; o; o >>= 1) v += __shfl_xor(v, o);
    if (t == 0) s_off = v;
  }
  __syncthreads();
  const int off = s_off;
  const int base = b * 1024 + t * 4;
  if (base + 3 < N_NODES) {
    int4 v = *(const int4*)(starts + base);
    v.x += off; v.y += off; v.z += off; v.w += off;
    *(int4*)(starts + base) = v;
    *(int4*)(pos + base) = v;
  } else {
    for (int i = 0; i < 4; ++i)
      if (base + i < N_NODES) {
        const int v = starts[base + i] + off;
        starts[base + i] = v;
        pos[base + i] = v;
      }
  }
  if (b == 0 && t == 0) starts[N_NODES] = N_EDGES;
}

__global__ void k_place(const int* __restrict__ ei, int* __restrict__ pos,
                        int* __restrict__ csr) {
  const int e = blockIdx.x * blockDim.x + threadIdx.x;
  if (e < N_EDGES) {
    const int d = ei[N_EDGES + e];
    const int slot = atomicAdd(&pos[d], 1);
    csr[slot] = e;
  }
}

// ---------------- gather-mean -> agg bf16 (8-wide MLP) ----------------
__global__ void __launch_bounds__(256) k_gather(const float* __restrict__ ea,
                                                const int* __restrict__ csr,
                                                const int* __restrict__ starts,
                                                unsigned short* __restrict__ aggb) {
  const int lane = threadIdx.x & 63;
  const int wv = threadIdx.x >> 6;
  const int wstride = gridDim.x * 4;
  for (int n = blockIdx.x * 4 + wv; n < N_NODES; n += wstride) {
    const int s0 = starts[n], s1 = starts[n + 1];
    float sum = 0.0f;
    int i = s0;
    for (; i + 7 < s1; i += 8) {
      int e[8];
#pragma unroll
      for (int j = 0; j < 8; ++j) e[j] = csr[i + j];
      float a[8];
#pragma unroll
      for (int j = 0; j < 8; ++j) a[j] = ea[(size_t)e[j] * 64 + lane];
      sum += ((a[0] + a[1]) + (a[2] + a[3])) + ((a[4] + a[5]) + (a[6] + a[7]));
    }
    for (; i + 3 < s1; i += 4) {
      const int e0 = csr[i], e1 = csr[i + 1], e2 = csr[i + 2], e3 = csr[i + 3];
      const float a0 = ea[(size_t)e0 * 64 + lane];
      const float a1 = ea[(size_t)e1 * 64 + lane];
      const float a2 = ea[(size_t)e2 * 64 + lane];
      const float a3 = ea[(size_t)e3 * 64 + lane];
      sum += (a0 + a1) + (a2 + a3);
    }
    for (; i < s1; ++i) sum += ea[(size_t)csr[i] * 64 + lane];
    const int deg = s1 - s0;
    aggb[(size_t)n * 64 + lane] = f2bf(sum / (float)max(deg, 1));
  }
}

// ---------------- fused node MLP: L0 -> LN -> L1 -> LN -> zb (bf16) ----------------
__global__ void __launch_bounds__(256) k_nodes(
    const float* __restrict__ x, const unsigned short* __restrict__ aggb,
    const unsigned short* __restrict__ W0T, const float* __restrict__ b0,
    const float* __restrict__ g0, const float* __restrict__ be0,
    const unsigned short* __restrict__ W1T, const float* __restrict__ b1,
    const float* __restrict__ g1, const float* __restrict__ be1,
    unsigned short* __restrict__ zb) {
  __shared__ char A0[64 * 256];   // [64][128] bf16, 256B rows, XOR-swizzled
  __shared__ char A1[64 * 384];   // [64][192] bf16, 384B rows, XOR-swizzled
  __shared__ float red0[64][4], red1[64][4];

  const int t = threadIdx.x;
  const int lane = t & 63;
  const int w = t >> 6;
  const int m = lane & 15;
  const int g = lane >> 4;
  const int nbase = blockIdx.x * 64;

  {
    const int row = t >> 2, seg = t & 3;
    const int node = nbase + row;
    const int swz = (row & 7) << 4;
    unsigned short h[16];
    if (node < N_NODES) {
      const float4* xr = (const float4*)(x + (size_t)node * 64 + seg * 16);
#pragma unroll
      for (int i = 0; i < 4; ++i) {
        const float4 v = xr[i];
        h[4 * i + 0] = f2bf(v.x); h[4 * i + 1] = f2bf(v.y);
        h[4 * i + 2] = f2bf(v.z); h[4 * i + 3] = f2bf(v.w);
      }
    } else {
#pragma unroll
      for (int i = 0; i < 16; ++i) h[i] = 0;
    }
    uint4 lo, hi;
    unsigned* lp = (unsigned*)&lo;
    unsigned* hp = (unsigned*)&hi;
#pragma unroll
    for (int i = 0; i < 4; ++i) lp[i] = (unsigned)h[2 * i] | ((unsigned)h[2 * i + 1] << 16);
#pragma unroll
    for (int i = 0; i < 4; ++i) hp[i] = (unsigned)h[8 + 2 * i] | ((unsigned)h[8 + 2 * i + 1] << 16);
    *(uint4*)(A0 + row * 256 + ((seg * 32) ^ swz)) = lo;
    *(uint4*)(A0 + row * 256 + ((seg * 32 + 16) ^ swz)) = hi;
    uint4 a0v = make_uint4(0, 0, 0, 0), a1v = make_uint4(0, 0, 0, 0);
    if (node < N_NODES) {
      const uint4* ap = (const uint4*)(aggb + (size_t)node * 64 + seg * 16);
      a0v = ap[0]; a1v = ap[1];
    }
    *(uint4*)(A0 + row * 256 + ((128 + seg * 32) ^ swz)) = a0v;
    *(uint4*)(A0 + row * 256 + ((128 + seg * 32 + 16) ^ swz)) = a1v;
    *(uint4*)(A1 + row * 384 + ((256 + seg * 32) ^ swz)) = a0v;
    *(uint4*)(A1 + row * 384 + ((256 + seg * 32 + 16) ^ swz)) = a1v;
  }

  short8 B0[4][2];
#pragma unroll
  for (int ks = 0; ks < 4; ++ks)
#pragma unroll
    for (int nt = 0; nt < 2; ++nt) {
      const int n = w * 32 + nt * 16 + m;
      B0[ks][nt] = *(const short8*)(W0T + n * 128 + ks * 32 + 8 * g);
    }

  __syncthreads();

  f32x4 acc0[4][2];
#pragma unroll
  for (int mt = 0; mt < 4; ++mt)
#pragma unroll
    for (int nt = 0; nt < 2; ++nt) acc0[mt][nt] = (f32x4){0.f, 0.f, 0.f, 0.f};
#pragma unroll
  for (int ks = 0; ks < 4; ++ks)
#pragma unroll
    for (int mt = 0; mt < 4; ++mt) {
      const int row = 16 * mt + m;
      const short8 a = *(const short8*)(A0 + row * 256 + ((ks * 64 + g * 16) ^ ((row & 7) << 4)));
      acc0[mt][0] = __builtin_amdgcn_mfma_f32_16x16x32_bf16(a, B0[ks][0], acc0[mt][0], 0, 0, 0);
      acc0[mt][1] = __builtin_amdgcn_mfma_f32_16x16x32_bf16(a, B0[ks][1], acc0[mt][1], 0, 0, 0);
    }

  float b0c[2], g0c[2], be0c[2];
#pragma unroll
  for (int nt = 0; nt < 2; ++nt) {
    const int c = w * 32 + nt * 16 + m;
    b0c[nt] = b0[c]; g0c[nt] = g0[c]; be0c[nt] = be0[c];
  }
  float ps1[4][4], ps2[4][4];
#pragma unroll
  for (int mt = 0; mt < 4; ++mt)
#pragma unroll
    for (int q = 0; q < 4; ++q) {
      const float v0 = fmaxf(acc0[mt][0][q] + b0c[0], 0.f);
      const float v1 = fmaxf(acc0[mt][1][q] + b0c[1], 0.f);
      ps1[mt][q] = v0 + v1;
      ps2[mt][q] = v0 * v0 + v1 * v1;
    }
#pragma unroll
  for (int mask = 1; mask <= 8; mask <<= 1)
#pragma unroll
    for (int mt = 0; mt < 4; ++mt)
#pragma unroll
      for (int q = 0; q < 4; ++q) {
        ps1[mt][q] += __shfl_xor(ps1[mt][q], mask);
        ps2[mt][q] += __shfl_xor(ps2[mt][q], mask);
      }
  if (m == 0) {
#pragma unroll
    for (int mt = 0; mt < 4; ++mt)
#pragma unroll
      for (int q = 0; q < 4; ++q) {
        const int row = 16 * mt + 4 * g + q;
        red0[row][w] = ps1[mt][q];
        red1[row][w] = ps2[mt][q];
      }
  }
  __syncthreads();

#pragma unroll
  for (int mt = 0; mt < 4; ++mt)
#pragma unroll
    for (int q = 0; q < 4; ++q) {
      const int row = 16 * mt + 4 * g + q;
      const float4 r0 = *(const float4*)red0[row];
      const float4 r1 = *(const float4*)red1[row];
      const float S1 = (r0.x + r0.y) + (r0.z + r0.w);
      const float S2 = (r1.x + r1.y) + (r1.z + r1.w);
      const float mean = S1 * (1.0f / 128.0f);
      const float var = S2 * (1.0f / 128.0f) - mean * mean;
      const float inv = rsqrtf(var + EPS);
#pragma unroll
      for (int nt = 0; nt < 2; ++nt) {
        const float v = fmaxf(acc0[mt][nt][q] + b0c[nt], 0.f);
        const float o = (v - mean) * inv * g0c[nt] + be0c[nt];
        const int col = w * 32 + nt * 16 + m;
        *(unsigned short*)(A1 + row * 384 + ((2 * col) ^ ((row & 7) << 4))) = f2bf(o);
      }
    }

  short8 B1[6];
  {
    const int n = w * 16 + m;
#pragma unroll
    for (int ks = 0; ks < 6; ++ks)
      B1[ks] = *(const short8*)(W1T + n * 192 + ks * 32 + 8 * g);
  }
  __syncthreads();

  f32x4 acc1[4];
#pragma unroll
  for (int mt = 0; mt < 4; ++mt) acc1[mt] = (f32x4){0.f, 0.f, 0.f, 0.f};
#pragma unroll
  for (int ks = 0; ks < 6; ++ks)
#pragma unroll
    for (int mt = 0; mt < 4; ++mt) {
      const int row = 16 * mt + m;
      const short8 a = *(const short8*)(A1 + row * 384 + ((ks * 64 + g * 16) ^ ((row & 7) << 4)));
      acc1[mt] = __builtin_amdgcn_mfma_f32_16x16x32_bf16(a, B1[ks], acc1[mt], 0, 0, 0);
    }

  const int c1i = w * 16 + m;
  const float b1c = b1[c1i], g1c = g1[c1i], be1c = be1[c1i];
  float qs1[4][4], qs2[4][4];
#pragma unroll
  for (int mt = 0; mt < 4; ++mt)
#pragma unroll
    for (int q = 0; q < 4; ++q) {
      const float v = fmaxf(acc1[mt][q] + b1c, 0.f);
      qs1[mt][q] = v;
      qs2[mt][q] = v * v;
    }
#pragma unroll
  for (int mask = 1; mask <= 8; mask <<= 1)
#pragma unroll
    for (int mt = 0; mt < 4; ++mt)
#pragma unroll
      for (int q = 0; q < 4; ++q) {
        qs1[mt][q] += __shfl_xor(qs1[mt][q], mask);
        qs2[mt][q] += __shfl_xor(qs2[mt][q], mask);
      }
  if (m == 0) {
#pragma unroll
    for (int mt = 0; mt < 4; ++mt)
#pragma unroll
      for (int q = 0; q < 4; ++q) {
        const int row = 16 * mt + 4 * g + q;
        red0[row][w] = qs1[mt][q];
        red1[row][w] = qs2[mt][q];
      }
  }
  __syncthreads();
#pragma unroll
  for (int mt = 0; mt < 4; ++mt)
#pragma unroll
    for (int q = 0; q < 4; ++q) {
      const int row = 16 * mt + 4 * g + q;
      const int node = nbase + row;
      const float4 r0 = *(const float4*)red0[row];
      const float4 r1 = *(const float4*)red1[row];
      const float S1 = (r0.x + r0.y) + (r0.z + r0.w);
      const float S2 = (r1.x + r1.y) + (r1.z + r1.w);
      const float mean = S1 * (1.0f / 64.0f);
      const float var = S2 * (1.0f / 64.0f) - mean * mean;
      const float inv = rsqrtf(var + EPS);
      const float v = fmaxf(acc1[mt][q] + b1c, 0.f);
      const float o = (v - mean) * inv * g1c + be1c;
      if (node < N_NODES) zb[(size_t)node * 64 + c1i] = f2bf(o);
    }
}

// ---------------- edge classifier: LDS-free direct-gather MFMA (R7 form) ----------------
__global__ void __launch_bounds__(256) k_cls_mfma(
    const unsigned short* __restrict__ zb, const int* __restrict__ ei,
    const unsigned short* __restrict__ Wc0T, const float* __restrict__ bc0,
    const float* __restrict__ Wc1, const float* __restrict__ bc1,
    float* __restrict__ out) {
  const int t = threadIdx.x;
  const int lane = t & 63;
  const int w = t >> 6;
  const int m = lane & 15;
  const int g = lane >> 4;

  short8 bfrag[4][4];
#pragma unroll
  for (int ks = 0; ks < 4; ++ks)
#pragma unroll
    for (int nt = 0; nt < 4; ++nt)
      bfrag[ks][nt] = *(const short8*)(Wc0T + (nt * 16 + m) * 128 + ks * 32 + 8 * g);
  float wc1v0[4], wc1v1[4], bc0v[4];
#pragma unroll
  for (int nt = 0; nt < 4; ++nt) {
    const int j = nt * 16 + m;
    wc1v0[nt] = Wc1[j * 2 + 0];
    wc1v1[nt] = Wc1[j * 2 + 1];
    bc0v[nt] = bc0[j];
  }
  const float ob0 = bc1[0], ob1 = bc1[1];

  const int gstride = gridDim.x * 4;
  for (int grp = blockIdx.x * 4 + w; grp < N_EDGES / 16; grp += gstride) {
    const int ebase = grp * 16;
    const int e = ebase + m;
    const int s = ei[e], d = ei[N_EDGES + e];
    const short8 a0 = *(const short8*)(zb + (size_t)s * 64 + 8 * g);
    const short8 a1 = *(const short8*)(zb + (size_t)s * 64 + 32 + 8 * g);
    const short8 a2 = *(const short8*)(zb + (size_t)d * 64 + 8 * g);
    const short8 a3 = *(const short8*)(zb + (size_t)d * 64 + 32 + 8 * g);

    f32x4 acc0 = {0.f, 0.f, 0.f, 0.f}, acc1 = acc0, acc2 = acc0, acc3 = acc0;
    acc0 = __builtin_amdgcn_mfma_f32_16x16x32_bf16(a0, bfrag[0][0], acc0, 0, 0, 0);
    acc1 = __builtin_amdgcn_mfma_f32_16x16x32_bf16(a0, bfrag[0][1], acc1, 0, 0, 0);
    acc2 = __builtin_amdgcn_mfma_f32_16x16x32_bf16(a0, bfrag[0][2], acc2, 0, 0, 0);
    acc3 = __builtin_amdgcn_mfma_f32_16x16x32_bf16(a0, bfrag[0][3], acc3, 0, 0, 0);
    acc0 = __builtin_amdgcn_mfma_f32_16x16x32_bf16(a1, bfrag[1][0], acc0, 0, 0, 0);
    acc1 = __builtin_amdgcn_mfma_f32_16x16x32_bf16(a1, bfrag[1][1], acc1, 0, 0, 0);
    acc2 = __builtin_amdgcn_mfma_f32_16x16x32_bf16(a1, bfrag[1][2], acc2, 0, 0, 0);
    acc3 = __builtin_amdgcn_mfma_f32_16x16x32_bf16(a1, bfrag[1][3], acc3, 0, 0, 0);
    acc0 = __builtin_amdgcn_mfma_f32_16x16x32_bf16(a2, bfrag[2][0], acc0, 0, 0, 0);
    acc1 = __builtin_amdgcn_mfma_f32_16x16x32_bf16(a2, bfrag[2][1], acc1, 0, 0, 0);
    acc2 = __builtin_amdgcn_mfma_f32_16x16x32_bf16(a2, bfrag[2][2], acc2, 0, 0, 0);
    acc3 = __builtin_amdgcn_mfma_f32_16x16x32_bf16(a2, bfrag[2][3], acc3, 0, 0, 0);
    acc0 = __builtin_amdgcn_mfma_f32_16x16x32_bf16(a3, bfrag[3][0], acc0, 0, 0, 0);
    acc1 = __builtin_amdgcn_mfma_f32_16x16x32_bf16(a3, bfrag[3][1], acc1, 0, 0, 0);
    acc2 = __builtin_amdgcn_mfma_f32_16x16x32_bf16(a3, bfrag[3][2], acc2, 0, 0, 0);
    acc3 = __builtin_amdgcn_mfma_f32_16x16x32_bf16(a3, bfrag[3][3], acc3, 0, 0, 0);

    float p0[4], p1[4];
#pragma unroll
    for (int r = 0; r < 4; ++r) {
      const float h0v = fmaxf(acc0[r] + bc0v[0], 0.f);
      const float h1v = fmaxf(acc1[r] + bc0v[1], 0.f);
      const float h2v = fmaxf(acc2[r] + bc0v[2], 0.f);
      const float h3v = fmaxf(acc3[r] + bc0v[3], 0.f);
      p0[r] = h0v * wc1v0[0] + h1v * wc1v0[1] + h2v * wc1v0[2] + h3v * wc1v0[3];
      p1[r] = h0v * wc1v1[0] + h1v * wc1v1[1] + h2v * wc1v1[2] + h3v * wc1v1[3];
    }
#pragma unroll
    for (int mask = 1; mask <= 8; mask <<= 1)
#pragma unroll
      for (int r = 0; r < 4; ++r) {
        p0[r] += __shfl_xor(p0[r], mask);
        p1[r] += __shfl_xor(p1[r], mask);
      }
    const int eout = ebase + g * 4;
#pragma unroll
    for (int r = 0; r < 4; ++r) {
      if (m == 2 * r) out[(size_t)(eout + r) * 2 + 0] = p0[r] + ob0;
      if (m == 2 * r + 1) out[(size_t)(eout + r) * 2 + 1] = p1[r] + ob1;
    }
  }
}

extern "C" void kernel_launch(void* const* d_in, const int* in_sizes, int n_in,
                              void* d_out, int out_size, void* d_ws, size_t ws_size,
                              hipStream_t stream) {
  const float* x   = (const float*)d_in[0];
  const int*   ei  = (const int*)d_in[1];
  const float* ea  = (const float*)d_in[2];
  const float* W0  = (const float*)d_in[3];
  const float* b0  = (const float*)d_in[4];
  const float* g0  = (const float*)d_in[5];
  const float* be0 = (const float*)d_in[6];
  const float* W1  = (const float*)d_in[7];
  const float* b1  = (const float*)d_in[8];
  const float* g1  = (const float*)d_in[9];
  const float* be1 = (const float*)d_in[10];
  const float* Wc0 = (const float*)d_in[11];
  const float* bc0 = (const float*)d_in[12];
  const float* Wc1 = (const float*)d_in[13];
  const float* bc1 = (const float*)d_in[14];
  float* out = (float*)d_out;

  char* base = (char*)d_ws;
  unsigned short* zb   = (unsigned short*)base;                       // N*64 bf16
  unsigned short* aggb = zb + (size_t)N_NODES * 64;                   // N*64 bf16
  unsigned short* W0T  = aggb + (size_t)N_NODES * 64;                 // 128*128
  unsigned short* W1T  = W0T + 128 * 128;                             // 64*192
  unsigned short* Wc0T = W1T + 64 * 192;                              // 64*128
  int* cnt    = (int*)(Wc0T + 64 * 128);                              // N
  int* starts = cnt + N_NODES;                                        // N+1 (+pad)
  int* pos    = starts + N_NODES + 4;                                 // N
  int* bsum   = pos + N_NODES;                                        // 64
  int* csr    = bsum + 64;                                            // E

  k_prep_count<<<3125, 256, 0, stream>>>(W0, W1, Wc0, W0T, W1T, Wc0T, ei, cnt);
  k_count2<<<(N_EDGES + 255) / 256, 256, 0, stream>>>(ei, cnt);
  k_scan_blk<<<SCAN_BLOCKS, 256, 0, stream>>>(cnt, starts, bsum);
  k_scan_add<<<SCAN_BLOCKS, 256, 0, stream>>>(starts, pos, bsum);
  k_place<<<(N_EDGES + 255) / 256, 256, 0, stream>>>(ei, pos, csr);
  k_gather<<<12500, 256, 0, stream>>>(ea, csr, starts, aggb);
  k_nodes<<<(N_NODES + 63) / 64, 256, 0, stream>>>(x, aggb, W0T, b0, g0, be0,
                                                   W1T, b1, g1, be1, zb);
  k_cls_mfma<<<2048, 256, 0, stream>>>(zb, ei, Wc0T, bc0, Wc1, bc1, out);
}

// Round 11
// 209.235 us; speedup vs baseline: 3.7488x; 1.8616x over previous
//
#include <hip/hip_runtime.h>
#include <hip/hip_bf16.h>

#define N_NODES 50000
#define N_EDGES 800000
#define EPS 1e-5f
#define SCAN_BLOCKS 49  // 49 * 1024 = 50176 >= N_NODES

typedef __attribute__((ext_vector_type(8))) short short8;
typedef __attribute__((ext_vector_type(4))) float f32x4;

static __device__ __forceinline__ unsigned short f2bf(float f) {
  union { float f; unsigned u; } v; v.f = f;
  const unsigned r = v.u + 0x7FFF + ((v.u >> 16) & 1);  // RNE
  return (unsigned short)(r >> 16);
}

// ---------------- weight prep (transpose + bf16) + cnt zero ----------------
__global__ void __launch_bounds__(256) k_prepw(
    const float* __restrict__ W0, const float* __restrict__ W1,
    const float* __restrict__ Wc0,
    unsigned short* __restrict__ W0T, unsigned short* __restrict__ W1T,
    unsigned short* __restrict__ Wc0T, int* __restrict__ cnt) {
  const int idx = blockIdx.x * 256 + threadIdx.x;
  if (idx < 128 * 128) {
    const int n = idx >> 7, k = idx & 127;
    W0T[idx] = f2bf(W0[k * 128 + n]);
  }
  if (idx < 64 * 192) {
    const int n = idx / 192, k = idx - n * 192;
    W1T[idx] = f2bf(W1[k * 64 + n]);
  }
  if (idx < 64 * 128) {
    const int n = idx >> 7, k = idx & 127;
    Wc0T[idx] = f2bf(Wc0[k * 64 + n]);
  }
  for (int i = idx; i < N_NODES; i += 64 * 256) cnt[i] = 0;
}

// ---------------- CSR build: count, scan(2-phase), place ----------------
__global__ void k_count(const int* __restrict__ ei, int* __restrict__ cnt) {
  const int e = blockIdx.x * blockDim.x + threadIdx.x;
  if (e < N_EDGES) atomicAdd(&cnt[ei[N_EDGES + e]], 1);
}

__global__ void __launch_bounds__(256) k_scan_blk(const int* __restrict__ cnt,
                                                  int* __restrict__ starts,
                                                  int* __restrict__ bsum) {
  __shared__ int lds[256];
  const int t = threadIdx.x, b = blockIdx.x;
  const int base = b * 1024 + t * 4;
  int c0 = 0, c1 = 0, c2 = 0, c3 = 0;
  if (base + 3 < N_NODES) {
    const int4 c = *(const int4*)(cnt + base);
    c0 = c.x; c1 = c.y; c2 = c.z; c3 = c.w;
  } else {
    if (base + 0 < N_NODES) c0 = cnt[base + 0];
    if (base + 1 < N_NODES) c1 = cnt[base + 1];
    if (base + 2 < N_NODES) c2 = cnt[base + 2];
    if (base + 3 < N_NODES) c3 = cnt[base + 3];
  }
  const int s = c0 + c1 + c2 + c3;
  lds[t] = s;
  __syncthreads();
  for (int off = 1; off < 256; off <<= 1) {
    const int v = (t >= off) ? lds[t - off] : 0;
    __syncthreads();
    lds[t] += v;
    __syncthreads();
  }
  int run = lds[t] - s;
  if (t == 255) bsum[b] = lds[255];  // block total
  const int o0 = run; run += c0;
  const int o1 = run; run += c1;
  const int o2 = run; run += c2;
  const int o3 = run;
  if (base + 3 < N_NODES) {
    *(int4*)(starts + base) = make_int4(o0, o1, o2, o3);
  } else {
    if (base + 0 < N_NODES) starts[base + 0] = o0;
    if (base + 1 < N_NODES) starts[base + 1] = o1;
    if (base + 2 < N_NODES) starts[base + 2] = o2;
    if (base + 3 < N_NODES) starts[base + 3] = o3;
  }
}

// adds sum(bsum[0..b)) computed in-kernel (49 values, one wave-reduce)
__global__ void __launch_bounds__(256) k_scan_add(int* __restrict__ starts,
                                                  int* __restrict__ pos,
                                                  const int* __restrict__ bsum) {
  __shared__ int s_off;
  const int t = threadIdx.x, b = blockIdx.x;
  if (t < 64) {
    int v = (t < b) ? bsum[t] : 0;  // b <= 48 < 64
    for (int o = 32; o; o >>= 1) v += __shfl_xor(v, o);
    if (t == 0) s_off = v;
  }
  __syncthreads();
  const int off = s_off;
  const int base = b * 1024 + t * 4;
  if (base + 3 < N_NODES) {
    int4 v = *(const int4*)(starts + base);
    v.x += off; v.y += off; v.z += off; v.w += off;
    *(int4*)(starts + base) = v;
    *(int4*)(pos + base) = v;
  } else {
    for (int i = 0; i < 4; ++i)
      if (base + i < N_NODES) {
        const int v = starts[base + i] + off;
        starts[base + i] = v;
        pos[base + i] = v;
      }
  }
  if (b == 0 && t == 0) starts[N_NODES] = N_EDGES;
}

__global__ void k_place(const int* __restrict__ ei, int* __restrict__ pos,
                        int* __restrict__ csr) {
  const int e = blockIdx.x * blockDim.x + threadIdx.x;
  if (e < N_EDGES) {
    const int d = ei[N_EDGES + e];
    const int slot = atomicAdd(&pos[d], 1);
    csr[slot] = e;
  }
}

// ---------------- gather-mean -> agg bf16 (8-wide MLP) ----------------
__global__ void __launch_bounds__(256) k_gather(const float* __restrict__ ea,
                                                const int* __restrict__ csr,
                                                const int* __restrict__ starts,
                                                unsigned short* __restrict__ aggb) {
  const int lane = threadIdx.x & 63;
  const int wv = threadIdx.x >> 6;
  const int wstride = gridDim.x * 4;
  for (int n = blockIdx.x * 4 + wv; n < N_NODES; n += wstride) {
    const int s0 = starts[n], s1 = starts[n + 1];
    float sum = 0.0f;
    int i = s0;
    for (; i + 7 < s1; i += 8) {
      int e[8];
#pragma unroll
      for (int j = 0; j < 8; ++j) e[j] = csr[i + j];
      float a[8];
#pragma unroll
      for (int j = 0; j < 8; ++j) a[j] = ea[(size_t)e[j] * 64 + lane];
      sum += ((a[0] + a[1]) + (a[2] + a[3])) + ((a[4] + a[5]) + (a[6] + a[7]));
    }
    for (; i + 3 < s1; i += 4) {
      const int e0 = csr[i], e1 = csr[i + 1], e2 = csr[i + 2], e3 = csr[i + 3];
      const float a0 = ea[(size_t)e0 * 64 + lane];
      const float a1 = ea[(size_t)e1 * 64 + lane];
      const float a2 = ea[(size_t)e2 * 64 + lane];
      const float a3 = ea[(size_t)e3 * 64 + lane];
      sum += (a0 + a1) + (a2 + a3);
    }
    for (; i < s1; ++i) sum += ea[(size_t)csr[i] * 64 + lane];
    const int deg = s1 - s0;
    aggb[(size_t)n * 64 + lane] = f2bf(sum / (float)max(deg, 1));
  }
}

// ---------------- fused node MLP: L0 -> LN -> L1 -> LN -> zb (bf16) ----------------
__global__ void __launch_bounds__(256) k_nodes(
    const float* __restrict__ x, const unsigned short* __restrict__ aggb,
    const unsigned short* __restrict__ W0T, const float* __restrict__ b0,
    const float* __restrict__ g0, const float* __restrict__ be0,
    const unsigned short* __restrict__ W1T, const float* __restrict__ b1,
    const float* __restrict__ g1, const float* __restrict__ be1,
    unsigned short* __restrict__ zb) {
  __shared__ char A0[64 * 256];   // [64][128] bf16, 256B rows, XOR-swizzled
  __shared__ char A1[64 * 384];   // [64][192] bf16, 384B rows, XOR-swizzled
  __shared__ float red0[64][4], red1[64][4];

  const int t = threadIdx.x;
  const int lane = t & 63;
  const int w = t >> 6;
  const int m = lane & 15;
  const int g = lane >> 4;
  const int nbase = blockIdx.x * 64;

  {
    const int row = t >> 2, seg = t & 3;
    const int node = nbase + row;
    const int swz = (row & 7) << 4;
    unsigned short h[16];
    if (node < N_NODES) {
      const float4* xr = (const float4*)(x + (size_t)node * 64 + seg * 16);
#pragma unroll
      for (int i = 0; i < 4; ++i) {
        const float4 v = xr[i];
        h[4 * i + 0] = f2bf(v.x); h[4 * i + 1] = f2bf(v.y);
        h[4 * i + 2] = f2bf(v.z); h[4 * i + 3] = f2bf(v.w);
      }
    } else {
#pragma unroll
      for (int i = 0; i < 16; ++i) h[i] = 0;
    }
    uint4 lo, hi;
    unsigned* lp = (unsigned*)&lo;
    unsigned* hp = (unsigned*)&hi;
#pragma unroll
    for (int i = 0; i < 4; ++i) lp[i] = (unsigned)h[2 * i] | ((unsigned)h[2 * i + 1] << 16);
#pragma unroll
    for (int i = 0; i < 4; ++i) hp[i] = (unsigned)h[8 + 2 * i] | ((unsigned)h[8 + 2 * i + 1] << 16);
    *(uint4*)(A0 + row * 256 + ((seg * 32) ^ swz)) = lo;
    *(uint4*)(A0 + row * 256 + ((seg * 32 + 16) ^ swz)) = hi;
    uint4 a0v = make_uint4(0, 0, 0, 0), a1v = make_uint4(0, 0, 0, 0);
    if (node < N_NODES) {
      const uint4* ap = (const uint4*)(aggb + (size_t)node * 64 + seg * 16);
      a0v = ap[0]; a1v = ap[1];
    }
    *(uint4*)(A0 + row * 256 + ((128 + seg * 32) ^ swz)) = a0v;
    *(uint4*)(A0 + row * 256 + ((128 + seg * 32 + 16) ^ swz)) = a1v;
    *(uint4*)(A1 + row * 384 + ((256 + seg * 32) ^ swz)) = a0v;
    *(uint4*)(A1 + row * 384 + ((256 + seg * 32 + 16) ^ swz)) = a1v;
  }

  short8 B0[4][2];
#pragma unroll
  for (int ks = 0; ks < 4; ++ks)
#pragma unroll
    for (int nt = 0; nt < 2; ++nt) {
      const int n = w * 32 + nt * 16 + m;
      B0[ks][nt] = *(const short8*)(W0T + n * 128 + ks * 32 + 8 * g);
    }

  __syncthreads();

  f32x4 acc0[4][2];
#pragma unroll
  for (int mt = 0; mt < 4; ++mt)
#pragma unroll
    for (int nt = 0; nt < 2; ++nt) acc0[mt][nt] = (f32x4){0.f, 0.f, 0.f, 0.f};
#pragma unroll
  for (int ks = 0; ks < 4; ++ks)
#pragma unroll
    for (int mt = 0; mt < 4; ++mt) {
      const int row = 16 * mt + m;
      const short8 a = *(const short8*)(A0 + row * 256 + ((ks * 64 + g * 16) ^ ((row & 7) << 4)));
      acc0[mt][0] = __builtin_amdgcn_mfma_f32_16x16x32_bf16(a, B0[ks][0], acc0[mt][0], 0, 0, 0);
      acc0[mt][1] = __builtin_amdgcn_mfma_f32_16x16x32_bf16(a, B0[ks][1], acc0[mt][1], 0, 0, 0);
    }

  float b0c[2], g0c[2], be0c[2];
#pragma unroll
  for (int nt = 0; nt < 2; ++nt) {
    const int c = w * 32 + nt * 16 + m;
    b0c[nt] = b0[c]; g0c[nt] = g0[c]; be0c[nt] = be0[c];
  }
  float ps1[4][4], ps2[4][4];
#pragma unroll
  for (int mt = 0; mt < 4; ++mt)
#pragma unroll
    for (int q = 0; q < 4; ++q) {
      const float v0 = fmaxf(acc0[mt][0][q] + b0c[0], 0.f);
      const float v1 = fmaxf(acc0[mt][1][q] + b0c[1], 0.f);
      ps1[mt][q] = v0 + v1;
      ps2[mt][q] = v0 * v0 + v1 * v1;
    }
#pragma unroll
  for (int mask = 1; mask <= 8; mask <<= 1)
#pragma unroll
    for (int mt = 0; mt < 4; ++mt)
#pragma unroll
      for (int q = 0; q < 4; ++q) {
        ps1[mt][q] += __shfl_xor(ps1[mt][q], mask);
        ps2[mt][q] += __shfl_xor(ps2[mt][q], mask);
      }
  if (m == 0) {
#pragma unroll
    for (int mt = 0; mt < 4; ++mt)
#pragma unroll
      for (int q = 0; q < 4; ++q) {
        const int row = 16 * mt + 4 * g + q;
        red0[row][w] = ps1[mt][q];
        red1[row][w] = ps2[mt][q];
      }
  }
  __syncthreads();

#pragma unroll
  for (int mt = 0; mt < 4; ++mt)
#pragma unroll
    for (int q = 0; q < 4; ++q) {
      const int row = 16 * mt + 4 * g + q;
      const float4 r0 = *(const float4*)red0[row];
      const float4 r1 = *(const float4*)red1[row];
      const float S1 = (r0.x + r0.y) + (r0.z + r0.w);
      const float S2 = (r1.x + r1.y) + (r1.z + r1.w);
      const float mean = S1 * (1.0f / 128.0f);
      const float var = S2 * (1.0f / 128.0f) - mean * mean;
      const float inv = rsqrtf(var + EPS);
#pragma unroll
      for (int nt = 0; nt < 2; ++nt) {
        const float v = fmaxf(acc0[mt][nt][q] + b0c[nt], 0.f);
        const float o = (v - mean) * inv * g0c[nt] + be0c[nt];
        const int col = w * 32 + nt * 16 + m;
        *(unsigned short*)(A1 + row * 384 + ((2 * col) ^ ((row & 7) << 4))) = f2bf(o);
      }
    }

  short8 B1[6];
  {
    const int n = w * 16 + m;
#pragma unroll
    for (int ks = 0; ks < 6; ++ks)
      B1[ks] = *(const short8*)(W1T + n * 192 + ks * 32 + 8 * g);
  }
  __syncthreads();

  f32x4 acc1[4];
#pragma unroll
  for (int mt = 0; mt < 4; ++mt) acc1[mt] = (f32x4){0.f, 0.f, 0.f, 0.f};
#pragma unroll
  for (int ks = 0; ks < 6; ++ks)
#pragma unroll
    for (int mt = 0; mt < 4; ++mt) {
      const int row = 16 * mt + m;
      const short8 a = *(const short8*)(A1 + row * 384 + ((ks * 64 + g * 16) ^ ((row & 7) << 4)));
      acc1[mt] = __builtin_amdgcn_mfma_f32_16x16x32_bf16(a, B1[ks], acc1[mt], 0, 0, 0);
    }

  const int c1i = w * 16 + m;
  const float b1c = b1[c1i], g1c = g1[c1i], be1c = be1[c1i];
  float qs1[4][4], qs2[4][4];
#pragma unroll
  for (int mt = 0; mt < 4; ++mt)
#pragma unroll
    for (int q = 0; q < 4; ++q) {
      const float v = fmaxf(acc1[mt][q] + b1c, 0.f);
      qs1[mt][q] = v;
      qs2[mt][q] = v * v;
    }
#pragma unroll
  for (int mask = 1; mask <= 8; mask <<= 1)
#pragma unroll
    for (int mt = 0; mt < 4; ++mt)
#pragma unroll
      for (int q = 0; q < 4; ++q) {
        qs1[mt][q] += __shfl_xor(qs1[mt][q], mask);
        qs2[mt][q] += __shfl_xor(qs2[mt][q], mask);
      }
  if (m == 0) {
#pragma unroll
    for (int mt = 0; mt < 4; ++mt)
#pragma unroll
      for (int q = 0; q < 4; ++q) {
        const int row = 16 * mt + 4 * g + q;
        red0[row][w] = qs1[mt][q];
        red1[row][w] = qs2[mt][q];
      }
  }
  __syncthreads();
#pragma unroll
  for (int mt = 0; mt < 4; ++mt)
#pragma unroll
    for (int q = 0; q < 4; ++q) {
      const int row = 16 * mt + 4 * g + q;
      const int node = nbase + row;
      const float4 r0 = *(const float4*)red0[row];
      const float4 r1 = *(const float4*)red1[row];
      const float S1 = (r0.x + r0.y) + (r0.z + r0.w);
      const float S2 = (r1.x + r1.y) + (r1.z + r1.w);
      const float mean = S1 * (1.0f / 64.0f);
      const float var = S2 * (1.0f / 64.0f) - mean * mean;
      const float inv = rsqrtf(var + EPS);
      const float v = fmaxf(acc1[mt][q] + b1c, 0.f);
      const float o = (v - mean) * inv * g1c + be1c;
      if (node < N_NODES) zb[(size_t)node * 64 + c1i] = f2bf(o);
    }
}

// ---------------- edge classifier: LDS-free direct-gather MFMA ----------------
__global__ void __launch_bounds__(256) k_cls_mfma(
    const unsigned short* __restrict__ zb, const int* __restrict__ ei,
    const unsigned short* __restrict__ Wc0T, const float* __restrict__ bc0,
    const float* __restrict__ Wc1, const float* __restrict__ bc1,
    float* __restrict__ out) {
  const int t = threadIdx.x;
  const int lane = t & 63;
  const int w = t >> 6;
  const int m = lane & 15;
  const int g = lane >> 4;

  short8 bfrag[4][4];
#pragma unroll
  for (int ks = 0; ks < 4; ++ks)
#pragma unroll
    for (int nt = 0; nt < 4; ++nt)
      bfrag[ks][nt] = *(const short8*)(Wc0T + (nt * 16 + m) * 128 + ks * 32 + 8 * g);
  float wc1v0[4], wc1v1[4], bc0v[4];
#pragma unroll
  for (int nt = 0; nt < 4; ++nt) {
    const int j = nt * 16 + m;
    wc1v0[nt] = Wc1[j * 2 + 0];
    wc1v1[nt] = Wc1[j * 2 + 1];
    bc0v[nt] = bc0[j];
  }
  const float ob0 = bc1[0], ob1 = bc1[1];

  const int gstride = gridDim.x * 4;
  for (int grp = blockIdx.x * 4 + w; grp < N_EDGES / 16; grp += gstride) {
    const int ebase = grp * 16;
    const int e = ebase + m;
    const int s = ei[e], d = ei[N_EDGES + e];
    const short8 a0 = *(const short8*)(zb + (size_t)s * 64 + 8 * g);
    const short8 a1 = *(const short8*)(zb + (size_t)s * 64 + 32 + 8 * g);
    const short8 a2 = *(const short8*)(zb + (size_t)d * 64 + 8 * g);
    const short8 a3 = *(const short8*)(zb + (size_t)d * 64 + 32 + 8 * g);

    f32x4 acc0 = {0.f, 0.f, 0.f, 0.f}, acc1 = acc0, acc2 = acc0, acc3 = acc0;
    acc0 = __builtin_amdgcn_mfma_f32_16x16x32_bf16(a0, bfrag[0][0], acc0, 0, 0, 0);
    acc1 = __builtin_amdgcn_mfma_f32_16x16x32_bf16(a0, bfrag[0][1], acc1, 0, 0, 0);
    acc2 = __builtin_amdgcn_mfma_f32_16x16x32_bf16(a0, bfrag[0][2], acc2, 0, 0, 0);
    acc3 = __builtin_amdgcn_mfma_f32_16x16x32_bf16(a0, bfrag[0][3], acc3, 0, 0, 0);
    acc0 = __builtin_amdgcn_mfma_f32_16x16x32_bf16(a1, bfrag[1][0], acc0, 0, 0, 0);
    acc1 = __builtin_amdgcn_mfma_f32_16x16x32_bf16(a1, bfrag[1][1], acc1, 0, 0, 0);
    acc2 = __builtin_amdgcn_mfma_f32_16x16x32_bf16(a1, bfrag[1][2], acc2, 0, 0, 0);
    acc3 = __builtin_amdgcn_mfma_f32_16x16x32_bf16(a1, bfrag[1][3], acc3, 0, 0, 0);
    acc0 = __builtin_amdgcn_mfma_f32_16x16x32_bf16(a2, bfrag[2][0], acc0, 0, 0, 0);
    acc1 = __builtin_amdgcn_mfma_f32_16x16x32_bf16(a2, bfrag[2][1], acc1, 0, 0, 0);
    acc2 = __builtin_amdgcn_mfma_f32_16x16x32_bf16(a2, bfrag[2][2], acc2, 0, 0, 0);
    acc3 = __builtin_amdgcn_mfma_f32_16x16x32_bf16(a2, bfrag[2][3], acc3, 0, 0, 0);
    acc0 = __builtin_amdgcn_mfma_f32_16x16x32_bf16(a3, bfrag[3][0], acc0, 0, 0, 0);
    acc1 = __builtin_amdgcn_mfma_f32_16x16x32_bf16(a3, bfrag[3][1], acc1, 0, 0, 0);
    acc2 = __builtin_amdgcn_mfma_f32_16x16x32_bf16(a3, bfrag[3][2], acc2, 0, 0, 0);
    acc3 = __builtin_amdgcn_mfma_f32_16x16x32_bf16(a3, bfrag[3][3], acc3, 0, 0, 0);

    float p0[4], p1[4];
#pragma unroll
    for (int r = 0; r < 4; ++r) {
      const float h0v = fmaxf(acc0[r] + bc0v[0], 0.f);
      const float h1v = fmaxf(acc1[r] + bc0v[1], 0.f);
      const float h2v = fmaxf(acc2[r] + bc0v[2], 0.f);
      const float h3v = fmaxf(acc3[r] + bc0v[3], 0.f);
      p0[r] = h0v * wc1v0[0] + h1v * wc1v0[1] + h2v * wc1v0[2] + h3v * wc1v0[3];
      p1[r] = h0v * wc1v1[0] + h1v * wc1v1[1] + h2v * wc1v1[2] + h3v * wc1v1[3];
    }
#pragma unroll
    for (int mask = 1; mask <= 8; mask <<= 1)
#pragma unroll
      for (int r = 0; r < 4; ++r) {
        p0[r] += __shfl_xor(p0[r], mask);
        p1[r] += __shfl_xor(p1[r], mask);
      }
    const int eout = ebase + g * 4;
#pragma unroll
    for (int r = 0; r < 4; ++r) {
      if (m == 2 * r) out[(size_t)(eout + r) * 2 + 0] = p0[r] + ob0;
      if (m == 2 * r + 1) out[(size_t)(eout + r) * 2 + 1] = p1[r] + ob1;
    }
  }
}

extern "C" void kernel_launch(void* const* d_in, const int* in_sizes, int n_in,
                              void* d_out, int out_size, void* d_ws, size_t ws_size,
                              hipStream_t stream) {
  const float* x   = (const float*)d_in[0];
  const int*   ei  = (const int*)d_in[1];
  const float* ea  = (const float*)d_in[2];
  const float* W0  = (const float*)d_in[3];
  const float* b0  = (const float*)d_in[4];
  const float* g0  = (const float*)d_in[5];
  const float* be0 = (const float*)d_in[6];
  const float* W1  = (const float*)d_in[7];
  const float* b1  = (const float*)d_in[8];
  const float* g1  = (const float*)d_in[9];
  const float* be1 = (const float*)d_in[10];
  const float* Wc0 = (const float*)d_in[11];
  const float* bc0 = (const float*)d_in[12];
  const float* Wc1 = (const float*)d_in[13];
  const float* bc1 = (const float*)d_in[14];
  float* out = (float*)d_out;

  char* base = (char*)d_ws;
  unsigned short* zb   = (unsigned short*)base;                       // N*64 bf16
  unsigned short* aggb = zb + (size_t)N_NODES * 64;                   // N*64 bf16
  unsigned short* W0T  = aggb + (size_t)N_NODES * 64;                 // 128*128
  unsigned short* W1T  = W0T + 128 * 128;                             // 64*192
  unsigned short* Wc0T = W1T + 64 * 192;                              // 64*128
  int* cnt    = (int*)(Wc0T + 64 * 128);                              // N
  int* starts = cnt + N_NODES;                                        // N+1 (+pad)
  int* pos    = starts + N_NODES + 4;                                 // N
  int* bsum   = pos + N_NODES;                                        // 64
  int* csr    = bsum + 64;                                            // E

  k_prepw<<<64, 256, 0, stream>>>(W0, W1, Wc0, W0T, W1T, Wc0T, cnt);
  k_count<<<(N_EDGES + 255) / 256, 256, 0, stream>>>(ei, cnt);
  k_scan_blk<<<SCAN_BLOCKS, 256, 0, stream>>>(cnt, starts, bsum);
  k_scan_add<<<SCAN_BLOCKS, 256, 0, stream>>>(starts, pos, bsum);
  k_place<<<(N_EDGES + 255) / 256, 256, 0, stream>>>(ei, pos, csr);
  k_gather<<<12500, 256, 0, stream>>>(ea, csr, starts, aggb);
  k_nodes<<<(N_NODES + 63) / 64, 256, 0, stream>>>(x, aggb, W0T, b0, g0, be0,
                                                   W1T, b1, g1, be1, zb);
  k_cls_mfma<<<2048, 256, 0, stream>>>(zb, ei, Wc0T, bc0, Wc1, bc1, out);
}